// Round 1
// baseline (1078.548 us; speedup 1.0000x reference)
//
#include <hip/hip_runtime.h>
#include <stdint.h>

// ---------------------------------------------------------------------------
// EncoderLayer (SST window attention + FFN), MI355X bf16-MFMA pipeline.
// K0 pack weights -> ws (B-fragment-linear bf16)
// K1 QKV projection: Q,K plain bf16 [tok][128]; V fragment-packed per window
// K3/K4 per-window attention (template: group1 V=48, group2 V=216) + LN1 -> out
// K5 FFN (128->512->128) + LN2, in-place on out
// ws layout (bytes): [0,98304) inproj frags | [98304,131072) Wo frags |
//   [131072,262144) W1 frags | [262144,393216) W2 frags | Q @524288 (300224 rows)
//   | K | VF group1 | VF group2.  Total ~248.5 MB.
// ---------------------------------------------------------------------------

#define DEV static __device__ __forceinline__

typedef __bf16 bf16_t;
typedef __attribute__((ext_vector_type(8))) __bf16 bf16x8;
typedef __attribute__((ext_vector_type(4))) float f32x4;
typedef __attribute__((ext_vector_type(8))) uint16_t u16x8;

constexpr int NHc = 8;
constexpr int NTOKc = 300000, TOK2c = 192000;
constexpr size_t WS_INPROJ_B = 0;
constexpr size_t WS_WO_B = 98304;
constexpr size_t WS_W1_B = 131072;
constexpr size_t WS_W2_B = 262144;
constexpr size_t WS_Q_B = 524288;
constexpr size_t QKBYTES = 300224ull * 256ull;          // padded rows for OOB frag reads
constexpr size_t WS_K_B = WS_Q_B + QKBYTES;
constexpr size_t WS_VF1_B = WS_K_B + QKBYTES;
constexpr size_t VF1BYTES = 4000ull * 8 * 2 * 1024;
constexpr size_t WS_VF2_B = WS_VF1_B + VF1BYTES;

DEV uint16_t f2bf(float f) {
  uint32_t u = __float_as_uint(f);
  u += 0x7fffu + ((u >> 16) & 1u);
  return (uint16_t)(u >> 16);
}
DEV float bf2f(uint16_t v) { return __uint_as_float(((uint32_t)v) << 16); }

DEV bf16x8 zero8() {
  bf16x8 z;
#pragma unroll
  for (int i = 0; i < 8; ++i) z[i] = (bf16_t)0.0f;
  return z;
}
DEV bf16x8 ldg8(const uint16_t* p) { return *(const bf16x8*)p; }

// store 4 floats as bf16 into swizzled LDS tile (leading dim ld elems)
DEV void stg4(uint16_t* buf, int row, int col, int ld, float x, float y, float z, float w) {
  int idx = (row * ld + col) ^ ((row & 7) << 3);
  uint64_t pk = (uint64_t)f2bf(x) | ((uint64_t)f2bf(y) << 16) |
                ((uint64_t)f2bf(z) << 32) | ((uint64_t)f2bf(w) << 48);
  *(uint64_t*)(buf + idx) = pk;
}

// --------------------------------------------------------------------- K0 ---
__global__ __launch_bounds__(64) void k_pack(const float* __restrict__ inw,
                                             const float* __restrict__ outw,
                                             const float* __restrict__ w1,
                                             const float* __restrict__ w2,
                                             uint16_t* __restrict__ wsb) {
  int b = blockIdx.x, l = threadIdx.x;
  const float* W;
  int Kd, c;
  size_t dst;
  if (b < 96)        { W = inw;  Kd = 128; c = b;       dst = (WS_INPROJ_B >> 1) + (size_t)c * 512; }
  else if (b < 128)  { W = outw; Kd = 128; c = b - 96;  dst = (WS_WO_B >> 1) + (size_t)c * 512; }
  else if (b < 256)  { W = w1;   Kd = 128; c = b - 128; dst = (WS_W1_B >> 1) + (size_t)c * 512; }
  else               { W = w2;   Kd = 512; c = b - 256; dst = (WS_W2_B >> 1) + (size_t)c * 512; }
  int nt, ks;
  if (Kd == 128) { nt = c >> 2; ks = c & 3; } else { nt = c >> 4; ks = c & 15; }
  int row = nt * 16 + (l & 15);
  int k0 = ks * 32 + ((l >> 4) << 3);
  uint16_t* d = wsb + dst + l * 8;
#pragma unroll
  for (int j = 0; j < 8; ++j) d[j] = f2bf(W[(size_t)row * Kd + k0 + j]);
}

// --------------------------------------------------------------------- K1 ---
__global__ __launch_bounds__(256, 2) void k_qkv(const float* __restrict__ src,
                                                const float* __restrict__ pos1,
                                                const float* __restrict__ pos2,
                                                const float* __restrict__ inpb,
                                                char* __restrict__ ws) {
  __shared__ uint16_t xb[64 * 128];
  __shared__ uint16_t qb[64 * 128];
  uint16_t* __restrict__ Qo = (uint16_t*)(ws + WS_Q_B);
  uint16_t* __restrict__ Ko = (uint16_t*)(ws + WS_K_B);
  uint16_t* __restrict__ Vf = (uint16_t*)ws;  // absolute u16 indexing
  const uint16_t* __restrict__ Wf = (const uint16_t*)ws;

  const int tid = threadIdx.x, l = tid & 63, wid = tid >> 6;
  const int lr = l & 15, lg = l >> 4;
  const int t0 = blockIdx.x * 64;
  const bool g2 = (t0 >= TOK2c);

  {
    int row = tid >> 2;
    int c0 = (tid & 3) * 32;
    int t = t0 + row;
    if (t < NTOKc) {
      const float* sp = src + (size_t)t * 128 + c0;
      const float* pp;
      if (!g2) { int w = t / 48, p = t - w * 48; pp = pos1 + ((size_t)w * 64 + p) * 128 + c0; }
      else     { int t2 = t - TOK2c; int w = t2 / 216, p = t2 - w * 216; pp = pos2 + ((size_t)w * 256 + p) * 128 + c0; }
#pragma unroll
      for (int k = 0; k < 8; ++k) {
        float4 xv = *(const float4*)(sp + 4 * k);
        float4 pv = *(const float4*)(pp + 4 * k);
        stg4(xb, row, c0 + 4 * k, 128, xv.x, xv.y, xv.z, xv.w);
        stg4(qb, row, c0 + 4 * k, 128, xv.x + pv.x, xv.y + pv.y, xv.z + pv.z, xv.w + pv.w);
      }
    } else {
#pragma unroll
      for (int k = 0; k < 8; ++k) {
        stg4(xb, row, c0 + 4 * k, 128, 0.f, 0.f, 0.f, 0.f);
        stg4(qb, row, c0 + 4 * k, 128, 0.f, 0.f, 0.f, 0.f);
      }
    }
  }
  __syncthreads();

  bf16x8 aq[4], ax[4];
#pragma unroll
  for (int ks = 0; ks < 4; ++ks) {
    int row = wid * 16 + lr, col = ks * 32 + lg * 8;
    int idx = (row * 128 + col) ^ ((row & 7) << 3);
    aq[ks] = *(const bf16x8*)(qb + idx);
    ax[ks] = *(const bf16x8*)(xb + idx);
  }

  int tok[4];
  bool val[4];
  size_t vbase[4];
  const size_t vstep = g2 ? (7 * 512) : (2 * 512);
#pragma unroll
  for (int r = 0; r < 4; ++r) {
    int t = t0 + wid * 16 + lg * 4 + r;
    tok[r] = t;
    val[r] = (t < NTOKc);
    int tt = val[r] ? t : 0;
    size_t base;
    int key;
    if (!g2) { int w = tt / 48; key = tt - w * 48; base = (WS_VF1_B >> 1) + ((size_t)w * 16 + (size_t)(key >> 5)) * 512; }
    else     { int t2 = tt - TOK2c; int w = t2 / 216; key = t2 - w * 216; base = (WS_VF2_B >> 1) + ((size_t)w * 56 + (size_t)(key >> 5)) * 512; }
    vbase[r] = base + (size_t)(((key & 31) >> 3) * 16) * 8 + (size_t)(key & 7);
  }

#pragma unroll
  for (int nt = 0; nt < 24; ++nt) {
    f32x4 c = {0.f, 0.f, 0.f, 0.f};
#pragma unroll
    for (int ks = 0; ks < 4; ++ks) {
      bf16x8 bfr = ldg8(Wf + (size_t)(nt * 4 + ks) * 512 + l * 8);
      c = __builtin_amdgcn_mfma_f32_16x16x32_bf16(nt < 16 ? aq[ks] : ax[ks], bfr, c, 0, 0, 0);
    }
    float bias = inpb[nt * 16 + lr];
    if (nt < 8) {
#pragma unroll
      for (int r = 0; r < 4; ++r)
        if (val[r]) Qo[(size_t)tok[r] * 128 + nt * 16 + lr] = f2bf(c[r] + bias);
    } else if (nt < 16) {
#pragma unroll
      for (int r = 0; r < 4; ++r)
        if (val[r]) Ko[(size_t)tok[r] * 128 + (nt - 8) * 16 + lr] = f2bf(c[r] + bias);
    } else {
      int h = nt - 16;
#pragma unroll
      for (int r = 0; r < 4; ++r)
        if (val[r]) Vf[vbase[r] + (size_t)h * vstep + (size_t)lr * 8] = f2bf(c[r] + bias);
    }
  }
}

// ------------------------------------------------------------------ K3/K4 ---
template <int NW, int VALID, int QT, int KT, int KSN, bool G2>
__global__ __launch_bounds__(NW * 64, 2) void k_attn(const float* __restrict__ src,
                                                     const float* __restrict__ bo,
                                                     const float* __restrict__ ln1w,
                                                     const float* __restrict__ ln1b,
                                                     const char* __restrict__ ws,
                                                     float* __restrict__ out) {
  extern __shared__ __align__(16) char smem[];
  uint16_t* O_lds = (uint16_t*)smem;  // [QT*16][128] bf16, xor-swizzled
  constexpr int OLDS_U16 = QT * 16 * 128;
  uint16_t* UN = (uint16_t*)smem + OLDS_U16;  // union: per-wave P buffers / O2

  const uint16_t* __restrict__ Qw = (const uint16_t*)(ws + WS_Q_B);
  const uint16_t* __restrict__ Kw = (const uint16_t*)(ws + WS_K_B);
  const uint16_t* __restrict__ VF = (const uint16_t*)(ws + (G2 ? WS_VF2_B : WS_VF1_B));
  const uint16_t* __restrict__ Wo = (const uint16_t*)(ws + WS_WO_B);

  const int w = blockIdx.x;
  const int tid = threadIdx.x, l = tid & 63, wid = tid >> 6;
  const int lr = l & 15, lg = l >> 4;
  const int wbase = (G2 ? TOK2c : 0) + w * VALID;
  uint16_t* pb = UN + (size_t)wid * (KSN * 512);

  for (int h = 0; h < NHc; ++h) {
    for (int qt = wid; qt < QT; qt += NW) {
      bf16x8 qf = ldg8(Qw + (size_t)(wbase + qt * 16 + lr) * 128 + h * 16 + ((lg & 1) << 3));
      if (l >= 32) qf = zero8();
      f32x4 s[KT];
#pragma unroll
      for (int kt = 0; kt < KT; ++kt) {
        bf16x8 kf = ldg8(Kw + (size_t)(wbase + kt * 16 + lr) * 128 + h * 16 + ((lg & 1) << 3));
        if (l >= 32) kf = zero8();
        f32x4 z = {0.f, 0.f, 0.f, 0.f};
        s[kt] = __builtin_amdgcn_mfma_f32_16x16x32_bf16(kf, qf, z, 0, 0, 0);
      }
      // softmax over keys (S^T strip: lane holds query col lr, keys over regs)
      float mx = -3.0e38f;
#pragma unroll
      for (int kt = 0; kt < KT; ++kt)
#pragma unroll
        for (int r = 0; r < 4; ++r) {
          int key = kt * 16 + lg * 4 + r;
          float v = s[kt][r] * 0.25f;
          v = (key < VALID) ? v : -1.0e30f;
          s[kt][r] = v;
          mx = fmaxf(mx, v);
        }
      mx = fmaxf(mx, __shfl_xor(mx, 16));
      mx = fmaxf(mx, __shfl_xor(mx, 32));
      float sum = 0.f;
#pragma unroll
      for (int kt = 0; kt < KT; ++kt)
#pragma unroll
        for (int r = 0; r < 4; ++r) {
          float p = __expf(s[kt][r] - mx);
          s[kt][r] = p;
          sum += p;
        }
      sum += __shfl_xor(sum, 16);
      sum += __shfl_xor(sum, 32);
      float rs = 1.0f / sum;
      // P^T into per-wave LDS buffer, B-fragment-linear
      u16x8 zz = {0, 0, 0, 0, 0, 0, 0, 0};
#pragma unroll
      for (int si = 0; si < KSN; ++si) *(u16x8*)(pb + (si * 64 + l) * 8) = zz;
#pragma unroll
      for (int kt = 0; kt < KT; ++kt)
#pragma unroll
        for (int r = 0; r < 4; ++r) {
          int key = kt * 16 + lg * 4 + r;
          pb[(key >> 5) * 512 + (((key & 31) >> 3) * 16 + lr) * 8 + (key & 7)] = f2bf(s[kt][r] * rs);
        }
      // PV: O^T tile = V^T * P^T
      f32x4 o = {0.f, 0.f, 0.f, 0.f};
      const size_t vblk = ((size_t)(w * 8 + h)) * ((size_t)KSN * 512);
#pragma unroll
      for (int si = 0; si < KSN; ++si) {
        bf16x8 vf = ldg8(VF + vblk + (si * 64 + l) * 8);
        bf16x8 pf = ldg8(pb + (si * 64 + l) * 8);
        o = __builtin_amdgcn_mfma_f32_16x16x32_bf16(vf, pf, o, 0, 0, 0);
      }
#pragma unroll
      for (int r = 0; r < 4; ++r) {
        int q = qt * 16 + lr, c = h * 16 + lg * 4 + r;
        O_lds[(q * 128 + c) ^ ((q & 7) << 3)] = f2bf(o[r]);
      }
    }
  }
  __syncthreads();
  // out-proj: out[q][do] = O[q][:] . Wo[do][:]
  uint16_t* O2 = UN;
  for (int qt = wid; qt < QT; qt += NW) {
#pragma unroll
    for (int nt = 0; nt < 8; ++nt) {
      f32x4 c = {0.f, 0.f, 0.f, 0.f};
#pragma unroll
      for (int ks = 0; ks < 4; ++ks) {
        int row = qt * 16 + lr, col = ks * 32 + lg * 8;
        bf16x8 af = *(const bf16x8*)(O_lds + ((row * 128 + col) ^ ((row & 7) << 3)));
        bf16x8 bfr = ldg8(Wo + (size_t)(nt * 4 + ks) * 512 + l * 8);
        c = __builtin_amdgcn_mfma_f32_16x16x32_bf16(af, bfr, c, 0, 0, 0);
      }
      float bias = bo[nt * 16 + lr];
#pragma unroll
      for (int r = 0; r < 4; ++r)
        O2[(qt * 16 + lg * 4 + r) * 128 + nt * 16 + lr] = f2bf(c[r] + bias);
    }
  }
  __syncthreads();
  // LN1(src + src2) -> out
  float lw0 = ln1w[2 * l], lw1 = ln1w[2 * l + 1];
  float lb0 = ln1b[2 * l], lb1 = ln1b[2 * l + 1];
  for (int row = wid; row < VALID; row += NW) {
    size_t t = (size_t)wbase + row;
    float2 xs = *(const float2*)(src + t * 128 + 2 * l);
    float a0 = xs.x + bf2f(O2[row * 128 + 2 * l]);
    float a1 = xs.y + bf2f(O2[row * 128 + 2 * l + 1]);
    float sm = a0 + a1, sq = a0 * a0 + a1 * a1;
#pragma unroll
    for (int m = 1; m < 64; m <<= 1) {
      sm += __shfl_xor(sm, m);
      sq += __shfl_xor(sq, m);
    }
    float mean = sm * 0.0078125f;
    float var = sq * 0.0078125f - mean * mean;
    float rstd = rsqrtf(var + 1e-5f);
    float2 yy;
    yy.x = (a0 - mean) * rstd * lw0 + lb0;
    yy.y = (a1 - mean) * rstd * lw1 + lb1;
    *(float2*)(out + t * 128 + 2 * l) = yy;
  }
}

// --------------------------------------------------------------------- K5 ---
__global__ __launch_bounds__(256, 2) void k_ffn(const float* __restrict__ b1v,
                                                const float* __restrict__ b2v,
                                                const float* __restrict__ ln2w,
                                                const float* __restrict__ ln2b,
                                                const char* __restrict__ ws,
                                                float* __restrict__ out) {
  __shared__ __align__(16) char sm[49152];
  uint16_t* x1b = (uint16_t*)sm;            // [32][128] bf16 swz, [0,8192)
  uint16_t* hb = (uint16_t*)(sm + 16384);   // [32][512] bf16 swz, [16384,49152)
  float* yb = (float*)sm;                   // [32][128] f32, overlaps dead x1b
  const uint16_t* __restrict__ W1f = (const uint16_t*)(ws + WS_W1_B);
  const uint16_t* __restrict__ W2f = (const uint16_t*)(ws + WS_W2_B);

  const int tid = threadIdx.x, l = tid & 63, wid = tid >> 6;
  const int lr = l & 15, lg = l >> 4;
  const size_t t0 = (size_t)blockIdx.x * 32;

  {
    int row = tid >> 3, c0 = (tid & 7) * 16;
    const float* p = out + (t0 + row) * 128 + c0;
#pragma unroll
    for (int k = 0; k < 4; ++k) {
      float4 v = *(const float4*)(p + 4 * k);
      stg4(x1b, row, c0 + 4 * k, 128, v.x, v.y, v.z, v.w);
    }
  }
  __syncthreads();
#pragma unroll
  for (int mt = 0; mt < 2; ++mt) {
    bf16x8 a[4];
#pragma unroll
    for (int ks = 0; ks < 4; ++ks) {
      int row = mt * 16 + lr, col = ks * 32 + lg * 8;
      a[ks] = *(const bf16x8*)(x1b + ((row * 128 + col) ^ ((row & 7) << 3)));
    }
#pragma unroll
    for (int n = 0; n < 8; ++n) {
      int nt = wid * 8 + n;
      f32x4 c = {0.f, 0.f, 0.f, 0.f};
#pragma unroll
      for (int ks = 0; ks < 4; ++ks) {
        bf16x8 bfr = ldg8(W1f + (size_t)(nt * 4 + ks) * 512 + l * 8);
        c = __builtin_amdgcn_mfma_f32_16x16x32_bf16(a[ks], bfr, c, 0, 0, 0);
      }
      float bias = b1v[nt * 16 + lr];
#pragma unroll
      for (int r = 0; r < 4; ++r) {
        int row = mt * 16 + lg * 4 + r, col = nt * 16 + lr;
        hb[(row * 512 + col) ^ ((row & 7) << 3)] = f2bf(fmaxf(c[r] + bias, 0.f));
      }
    }
  }
  __syncthreads();
#pragma unroll
  for (int i = 0; i < 4; ++i) {
    int mt = i >> 1, nt = wid * 2 + (i & 1);
    f32x4 c = {0.f, 0.f, 0.f, 0.f};
#pragma unroll
    for (int ks = 0; ks < 16; ++ks) {
      int row = mt * 16 + lr, col = ks * 32 + lg * 8;
      bf16x8 af = *(const bf16x8*)(hb + ((row * 512 + col) ^ ((row & 7) << 3)));
      bf16x8 bfr = ldg8(W2f + (size_t)(nt * 16 + ks) * 512 + l * 8);
      c = __builtin_amdgcn_mfma_f32_16x16x32_bf16(af, bfr, c, 0, 0, 0);
    }
    float bias = b2v[nt * 16 + lr];
#pragma unroll
    for (int r = 0; r < 4; ++r)
      yb[(mt * 16 + lg * 4 + r) * 128 + nt * 16 + lr] = c[r] + bias;
  }
  __syncthreads();
  float lw0 = ln2w[2 * l], lw1 = ln2w[2 * l + 1];
  float lb0 = ln2b[2 * l], lb1 = ln2b[2 * l + 1];
  for (int row = wid; row < 32; row += 4) {
    size_t t = t0 + row;
    float2 xs = *(const float2*)(out + t * 128 + 2 * l);
    float a0 = xs.x + yb[row * 128 + 2 * l];
    float a1 = xs.y + yb[row * 128 + 2 * l + 1];
    float sm2 = a0 + a1, sq = a0 * a0 + a1 * a1;
#pragma unroll
    for (int m = 1; m < 64; m <<= 1) {
      sm2 += __shfl_xor(sm2, m);
      sq += __shfl_xor(sq, m);
    }
    float mean = sm2 * 0.0078125f;
    float var = sq * 0.0078125f - mean * mean;
    float rstd = rsqrtf(var + 1e-5f);
    float2 yy;
    yy.x = (a0 - mean) * rstd * lw0 + lb0;
    yy.y = (a1 - mean) * rstd * lw1 + lb1;
    *(float2*)(out + t * 128 + 2 * l) = yy;
  }
}

// ---------------------------------------------------------------------------
extern "C" void kernel_launch(void* const* d_in, const int* in_sizes, int n_in,
                              void* d_out, int out_size, void* d_ws, size_t ws_size,
                              hipStream_t stream) {
  (void)in_sizes; (void)n_in; (void)out_size; (void)ws_size;
  const float* src  = (const float*)d_in[0];
  const float* pos1 = (const float*)d_in[1];
  const float* pos2 = (const float*)d_in[2];
  const float* inw  = (const float*)d_in[3];
  const float* inb  = (const float*)d_in[4];
  const float* outw = (const float*)d_in[5];
  const float* outb = (const float*)d_in[6];
  const float* w1   = (const float*)d_in[7];
  const float* b1   = (const float*)d_in[8];
  const float* w2   = (const float*)d_in[9];
  const float* b2   = (const float*)d_in[10];
  const float* ln1w = (const float*)d_in[11];
  const float* ln1b = (const float*)d_in[12];
  const float* ln2w = (const float*)d_in[13];
  const float* ln2b = (const float*)d_in[14];
  float* out = (float*)d_out;
  char* ws = (char*)d_ws;

  k_pack<<<384, 64, 0, stream>>>(inw, outw, w1, w2, (uint16_t*)ws);
  k_qkv<<<4688, 256, 0, stream>>>(src, pos1, pos2, inb, ws);
  k_attn<3, 48, 3, 3, 2, false><<<4000, 192, 24576, stream>>>(src, outb, ln1w, ln1b, ws, out);
  (void)hipFuncSetAttribute((const void*)k_attn<8, 216, 14, 14, 7, true>,
                            hipFuncAttributeMaxDynamicSharedMemorySize, 114688);
  k_attn<8, 216, 14, 14, 7, true><<<500, 512, 114688, stream>>>(src, outb, ln1w, ln1b, ws, out);
  k_ffn<<<9375, 256, 0, stream>>>(b1, b2, ln2w, ln2b, ws, out);
}